// Round 11
// baseline (661.695 us; speedup 1.0000x reference)
//
#include <hip/hip_runtime.h>
#include <math.h>

#define DD 768
#define QN 64
#define TN 32            // docs per tile
#define BK 256           // k-floats per slice = 1 KB per doc row per slice
#define NSLICE 3
#define TOPK 10
#define CAND 32
#define NBLK 256

// LDS arena: qn [64][1536B] = 96 KB @0 | doc slice dbuf 2 x [32][512B] = 32 KB @98304
#define QOFF 0
#define DOFF 98304
#define DBUF0 (DOFF)
#define DBUF1 (DOFF + 16384)
// scb [64][33] f32 (8448 B) overlays DBUF0

typedef short bf16x8 __attribute__((ext_vector_type(8)));
typedef float f32x4  __attribute__((ext_vector_type(4)));

// float -> bf16 round-to-nearest-even
__device__ __forceinline__ unsigned short f2bf(float f) {
    unsigned int u = __float_as_uint(f);
    u = (u + 0x7fffu + ((u >> 16) & 1u)) >> 16;
    return (unsigned short)u;
}
__device__ __forceinline__ unsigned pk2(float a, float b) {
    return (unsigned)f2bf(a) | ((unsigned)f2bf(b) << 16);
}

// lgkm-only barrier: LDS ops drained, global loads (private regs) stay in flight
#define LGKMBAR() do { asm volatile("s_waitcnt lgkmcnt(0)" ::: "memory"); \
                       __builtin_amdgcn_s_barrier(); } while (0)

// ---------------------------------------------------------------------------
__device__ __forceinline__ void topk_insert(float (&sc)[TOPK], int (&id)[TOPK],
                                            float v, int nid) {
    if (v <= sc[TOPK - 1]) return;
#pragma unroll
    for (int j = TOPK - 1; j >= 1; --j) {
        bool gtj   = v > sc[j];
        bool gtjm1 = v > sc[j - 1];
        float cs = gtjm1 ? sc[j - 1] : v;
        int   ci = gtjm1 ? id[j - 1] : nid;
        sc[j] = gtj ? cs : sc[j];
        id[j] = gtj ? ci : id[j];
    }
    bool gt0 = v > sc[0];
    sc[0] = gt0 ? v : sc[0];
    id[0] = gt0 ? nid : id[0];
}

// ---------------------------------------------------------------------------
// Phase 0: L2-normalize queries (fp32 math), emit bf16 [64][768]
// ---------------------------------------------------------------------------
__global__ void qnorm_kernel(const float* __restrict__ q,
                             unsigned short* __restrict__ qn) {
    const int row = blockIdx.x;
    const int t = threadIdx.x;  // 256
    float vals[3];
    float s = 0.f;
#pragma unroll
    for (int i = 0; i < 3; ++i) {
        vals[i] = q[row * DD + i * 256 + t];
        s += vals[i] * vals[i];
    }
#pragma unroll
    for (int o = 32; o; o >>= 1) s += __shfl_down(s, o);
    __shared__ float red[4];
    if ((t & 63) == 0) red[t >> 6] = s;
    __syncthreads();
    float tot = red[0] + red[1] + red[2] + red[3];
    float inv = 1.f / fmaxf(sqrtf(tot), 1e-12f);
#pragma unroll
    for (int i = 0; i < 3; ++i)
        qn[row * DD + i * 256 + t] = f2bf(vals[i] * inv);
}

// ---------------------------------------------------------------------------
// Phase 1: MFMA bf16 approx scores (filter). Contiguous-stream redesign:
// TN=32 docs x BK=256 slices -> 1 KB/row/slice HBM segments (DRAM-page
// friendly), whole bf16 query matrix staged ONCE in LDS (96 KB), doc slices
// register-staged (1 KB contiguous per wave-instr) into a 2x16KB LDS dbuf,
// lgkm-only barriers (prefetch regs never drained at barriers). 512 thr,
// 8 waves = 4m x 2n frags, 1 block/CU. Doc norms free in staging regs.
// ---------------------------------------------------------------------------
__global__ __launch_bounds__(512, 1)
void score_kernel(const unsigned short* __restrict__ qn,
                  const float* __restrict__ docs,
                  float* __restrict__ cand_sc, int* __restrict__ cand_id,
                  int Ndocs, int ntiles, int niter) {
    __shared__ char arena[131072];
    __shared__ float dinv[TN];
    float* scb = (float*)(arena + DOFF);   // [64][33] overlay on DBUF0

    const int tid  = threadIdx.x;
    const int lane = tid & 63;
    const int wv   = tid >> 6;    // 0..7
    const int wm   = wv >> 1;     // m-frag: q rows [wm*16, +16)
    const int wn   = wv & 1;      // n-frag: docs  [wn*16, +16)
    const int fr   = lane & 15;
    const int fk   = lane >> 4;
    const int bid  = blockIdx.x;

    // ---- stage whole query matrix qn -> LDS (96 KB, once) ----
    {
        const int row = tid >> 3, seg = tid & 7;
#pragma unroll
        for (int j = 0; j < 12; ++j) {
            uint4 v = *(const uint4*)(qn + row * DD + seg * 96 + j * 8);
            int B = seg * 192 + j * 16;
            *(uint4*)(arena + QOFF + row * 1536 + (B ^ ((row & 7) << 4))) = v;
        }
    }

    float sc[TOPK];
    int   id[TOPK];
#pragma unroll
    for (int j = 0; j < TOPK; ++j) { sc[j] = -INFINITY; id[j] = 0; }

    f32x4 acc;
#pragma unroll
    for (int v = 0; v < 4; ++v) acc[v] = 0.f;
    float dnp[4] = {0.f, 0.f, 0.f, 0.f};
    float4 rbA[4], rbB[4];

    // load slice s of tile t: wave stages rows [wv*4, +4), lane covers bytes
    // lane*16 of each row's 1 KB slice chunk -> 1 KB contiguous per instr
    auto LOADS = [&](float4 (&rb)[4], int t, int s) {
        int tc = t < ntiles ? t : ntiles - 1;
#pragma unroll
        for (int j = 0; j < 4; ++j) {
            int r = tc * TN + wv * 4 + j;
            r = r < Ndocs ? r : Ndocs - 1;
            rb[j] = *(const float4*)(docs + (size_t)r * DD + s * BK + lane * 4);
        }
    };
    // convert + write to LDS doc buf (8B granule, XOR-swizzled); accum sumsq
    auto STOREB = [&](float4 (&rb)[4], int boff) {
#pragma unroll
        for (int j = 0; j < 4; ++j) {
            int r = wv * 4 + j;
            float4 a = rb[j];
            dnp[j] += a.x * a.x + a.y * a.y + a.z * a.z + a.w * a.w;
            uint2 w2;
            w2.x = pk2(a.x, a.y);
            w2.y = pk2(a.z, a.w);
            *(uint2*)(arena + boff + r * 512 + ((lane * 8) ^ ((r & 7) << 4))) = w2;
        }
    };
    // 8 MFMA over the slice: wave computes (16q x 16d) x K=256
    auto MM = [&](int boff, int soff) {
#pragma unroll
        for (int kc = 0; kc < 8; ++kc) {
            int ar = wm * 16 + fr;
            bf16x8 af = *(const bf16x8*)(arena + QOFF + ar * 1536 +
                         ((soff + kc * 64 + fk * 16) ^ ((ar & 7) << 4)));
            int br = wn * 16 + fr;
            bf16x8 bf = *(const bf16x8*)(arena + boff + br * 512 +
                         ((kc * 64 + fk * 16) ^ ((br & 7) << 4)));
            acc = __builtin_amdgcn_mfma_f32_16x16x32_bf16(af, bf, acc, 0, 0, 0);
        }
    };
    // per-tile epilogue: norms (shfl), scale+scatter to scb, serial scan
    auto EPI = [&](int t) {
#pragma unroll
        for (int j = 0; j < 4; ++j) {
            float s = dnp[j];
            s += __shfl_xor(s, 1);  s += __shfl_xor(s, 2);
            s += __shfl_xor(s, 4);  s += __shfl_xor(s, 8);
            s += __shfl_xor(s, 16); s += __shfl_xor(s, 32);
            if (lane == 0) dinv[wv * 4 + j] = 1.f / fmaxf(sqrtf(s), 1e-12f);
            dnp[j] = 0.f;
        }
        LGKMBAR();   // dinv visible; all MM reads of DBUF0 done (scb overlay safe)
        {
            int dcol = wn * 16 + fr;
            float di = dinv[dcol];
#pragma unroll
            for (int v = 0; v < 4; ++v) {
                scb[(wm * 16 + fk * 4 + v) * 33 + dcol] = acc[v] * di;
                acc[v] = 0.f;
            }
        }
        LGKMBAR();   // scb complete
        if (tid < QN && t < ntiles) {
            int d0g = t * TN;
            int lim = Ndocs - d0g;
            if (lim > TN) lim = TN;
            for (int j = 0; j < lim; ++j)
                topk_insert(sc, id, scb[tid * 33 + j], d0g + j);
        }
        LGKMBAR();   // scan reads done before any STORE touches DBUF0
    };

    // ---- prologue ----
    LOADS(rbA, bid, 0);
    LOADS(rbB, bid, 1);

    // ---- main loop: 2 tiles per iteration (static reg/buffer ping-pong) ----
    for (int it = 0; it < niter; ++it) {
        const int tA = bid + (2 * it) * gridDim.x;
        const int tB = tA + gridDim.x;
        const int tC = tB + gridDim.x;
        // tile A: slices -> buf0, buf1, buf0
        STOREB(rbA, DBUF0); LOADS(rbA, tA, 2); LGKMBAR(); MM(DBUF0, 0);
        STOREB(rbB, DBUF1); LOADS(rbB, tB, 0); LGKMBAR(); MM(DBUF1, 512);
        STOREB(rbA, DBUF0); LOADS(rbA, tB, 1); LGKMBAR(); MM(DBUF0, 1024);
        EPI(tA);
        // tile B: slices -> buf1, buf0, buf1
        STOREB(rbB, DBUF1); LOADS(rbB, tB, 2); LGKMBAR(); MM(DBUF1, 0);
        STOREB(rbA, DBUF0); LOADS(rbA, tC, 0); LGKMBAR(); MM(DBUF0, 512);
        STOREB(rbB, DBUF1); LOADS(rbB, tC, 1); LGKMBAR(); MM(DBUF1, 1024);
        EPI(tB);
    }

    if (tid < QN) {
        size_t base = ((size_t)bid * QN + tid) * TOPK;
#pragma unroll
        for (int j = 0; j < TOPK; ++j) {
            cand_sc[base + j] = sc[j];
            cand_id[base + j] = id[j];
        }
    }
}

// ---------------------------------------------------------------------------
// Phase 2: per query, reduce nlists sorted 10-lists -> global approx top-32.
// ---------------------------------------------------------------------------
__global__ __launch_bounds__(256)
void merge32_kernel(const float* __restrict__ cand_sc,
                    const int* __restrict__ cand_id,
                    int* __restrict__ cand32, int nlists) {
    const int q = blockIdx.x;
    const int t = threadIdx.x;  // 256
    __shared__ float lsc[256 * CAND];  // 32 KB
    __shared__ int   lid[256 * CAND];  // 32 KB
    const int base = t * CAND;
#pragma unroll
    for (int j = 0; j < CAND; ++j) { lsc[base + j] = -INFINITY; lid[base + j] = 0; }

    for (int b = t; b < nlists; b += 256) {
        size_t g = ((size_t)b * QN + q) * TOPK;
        for (int j = 0; j < TOPK; ++j) {
            float v = cand_sc[g + j];
            if (v <= lsc[base + CAND - 1]) break;   // list sorted desc
            int idv = cand_id[g + j];
            int p = CAND - 1;
            while (p > 0 && lsc[base + p - 1] < v) {
                lsc[base + p] = lsc[base + p - 1];
                lid[base + p] = lid[base + p - 1];
                --p;
            }
            lsc[base + p] = v;
            lid[base + p] = idv;
        }
    }
    __syncthreads();

    for (int s = 128; s >= 1; s >>= 1) {
        if (t < s) {
            int ia = 0, ib = 0;
            float rsv[CAND];
            int   riv[CAND];
#pragma unroll
            for (int j = 0; j < CAND; ++j) {
                float va = lsc[t * CAND + ia];
                float vb = lsc[(t + s) * CAND + ib];
                bool ta = va >= vb;
                rsv[j] = ta ? va : vb;
                riv[j] = ta ? lid[t * CAND + ia] : lid[(t + s) * CAND + ib];
                ia += ta ? 1 : 0;
                ib += ta ? 0 : 1;
            }
#pragma unroll
            for (int j = 0; j < CAND; ++j) {
                lsc[t * CAND + j] = rsv[j];
                lid[t * CAND + j] = riv[j];
            }
        }
        __syncthreads();
    }
    if (t < CAND) cand32[q * CAND + t] = lid[t];
}

// ---------------------------------------------------------------------------
// Phase 3: exact fp32 rescore of 32 candidates per query (double accumulate),
// final top-10 by rank-count with (score desc, index asc) tie-break.
// ---------------------------------------------------------------------------
__global__ __launch_bounds__(256)
void rescore_kernel(const float* __restrict__ q, const float* __restrict__ docs,
                    const int* __restrict__ cand32, float* __restrict__ out,
                    int score_off) {
    const int qi = blockIdx.x;
    const int t = threadIdx.x, lane = t & 63, wv = t >> 6;
    __shared__ float qbuf[DD];
    __shared__ float red[4];
    __shared__ float csc[CAND];
    __shared__ int   cid[CAND];

    float v[3];
    float ss = 0.f;
#pragma unroll
    for (int i = 0; i < 3; ++i) {
        v[i] = q[qi * DD + i * 256 + t];
        ss += v[i] * v[i];
    }
#pragma unroll
    for (int o = 32; o; o >>= 1) ss += __shfl_down(ss, o);
    if (lane == 0) red[wv] = ss;
    __syncthreads();
    float qnorm = fmaxf(sqrtf(red[0] + red[1] + red[2] + red[3]), 1e-12f);
#pragma unroll
    for (int i = 0; i < 3; ++i) qbuf[i * 256 + t] = v[i] / qnorm;
    __syncthreads();

    for (int c = wv; c < CAND; c += 4) {
        const int d = cand32[qi * CAND + c];
        const float* dp = docs + (size_t)d * DD;
        float dss = 0.f;
#pragma unroll
        for (int j = 0; j < 3; ++j) {
            float4 dv = *(const float4*)(dp + j * 256 + lane * 4);
            dss += dv.x * dv.x + dv.y * dv.y + dv.z * dv.z + dv.w * dv.w;
        }
#pragma unroll
        for (int o = 32; o; o >>= 1) dss += __shfl_down(dss, o);
        dss = __shfl(dss, 0);
        float dnorm = fmaxf(sqrtf(dss), 1e-12f);
        double dot = 0.0;
#pragma unroll
        for (int j = 0; j < 3; ++j) {
            float4 dv = *(const float4*)(dp + j * 256 + lane * 4);
            float4 qv = *(const float4*)(qbuf + j * 256 + lane * 4);
            float d0 = dv.x / dnorm, d1 = dv.y / dnorm;
            float d2 = dv.z / dnorm, d3 = dv.w / dnorm;
            dot += (double)d0 * qv.x + (double)d1 * qv.y
                 + (double)d2 * qv.z + (double)d3 * qv.w;
        }
#pragma unroll
        for (int o = 32; o; o >>= 1) dot += __shfl_down(dot, o);
        if (lane == 0) { csc[c] = (float)dot; cid[c] = d; }
    }
    __syncthreads();

    if (t < CAND) {
        float s = csc[t];
        int myid = cid[t];
        int rank = 0;
        for (int j = 0; j < CAND; ++j) {
            float sj = csc[j];
            int ij = cid[j];
            rank += ((sj > s) || (sj == s && ij < myid)) ? 1 : 0;
        }
        if (rank < TOPK) {
            out[qi * TOPK + rank] = (float)myid;
            out[score_off + qi * TOPK + rank] = s;
        }
    }
}

// ---------------------------------------------------------------------------
extern "C" void kernel_launch(void* const* d_in, const int* in_sizes, int n_in,
                              void* d_out, int out_size, void* d_ws, size_t ws_size,
                              hipStream_t stream) {
    const float* q    = (const float*)d_in[0];
    const float* docs = (const float*)d_in[1];
    const int N = in_sizes[1] / DD;   // 500000

    // ws: qn bf16 [64*768] | cand32 int [64*32] | cand_sc f32 | cand_id i32
    unsigned short* qn = (unsigned short*)d_ws;
    const size_t qbytes = (size_t)QN * DD * 2;
    int* cand32 = (int*)((char*)d_ws + qbytes);
    const size_t c32bytes = (size_t)QN * CAND * 4;

    size_t used = qbytes + c32bytes;
    size_t avail = (ws_size > used) ? (ws_size - used) : 0;
    size_t per_list = (size_t)QN * TOPK * 8;
    int ntiles = (N + TN - 1) / TN;          // 15625
    int nblk = NBLK;
    if ((size_t)nblk * per_list > avail) nblk = (int)(avail / per_list);
    if (nblk < 1) nblk = 1;
    if (nblk > ntiles) nblk = ntiles;
    int tpb = (ntiles + nblk - 1) / nblk;    // 62
    int niter = (tpb + 1) / 2;               // 31

    float* cand_sc = (float*)((char*)d_ws + used);
    int*   cand_id = (int*)(cand_sc + (size_t)nblk * QN * TOPK);

    hipLaunchKernelGGL(qnorm_kernel, dim3(QN), dim3(256), 0, stream, q, qn);
    hipLaunchKernelGGL(score_kernel, dim3(nblk), dim3(512), 0, stream,
                       qn, docs, cand_sc, cand_id, N, ntiles, niter);
    hipLaunchKernelGGL(merge32_kernel, dim3(QN), dim3(256), 0, stream,
                       cand_sc, cand_id, cand32, nblk);
    hipLaunchKernelGGL(rescore_kernel, dim3(QN), dim3(256), 0, stream,
                       q, docs, cand32, (float*)d_out, out_size / 2);
}